// Round 20
// baseline (129.641 us; speedup 1.0000x reference)
//
#include <hip/hip_runtime.h>
#include <math.h>

#define NTOK 32768
#define KCB  1024
#define DIM  64

typedef __attribute__((ext_vector_type(8))) short short8;
typedef __attribute__((ext_vector_type(4))) float f32x4;
#define MFMA __builtin_amdgcn_mfma_f32_16x16x32_bf16
#define ALOAD(p) __hip_atomic_load((p), __ATOMIC_RELAXED, __HIP_MEMORY_SCOPE_AGENT)

// ---- workspace layout (float word offsets) ----
#define WS_XR      0                       // [NTOK*64] rotated vectors f32
#define WS_ENORM   2097152                 // [1024] ||e_k||^2
#define WS_EH      2098176                 // [32768 words] E hi bf16
#define WS_EM      2130944                 // [32768 words] E mid bf16
#define WS_EL      2163712                 // [32768 words] E lo bf16
#define WS_COUNTS  2196480                 // [1024] counts (final)
#define WS_CS      2197504                 // [1024] smoothed cluster size
#define WS_XRSUM   2198528                 // [512] 8 replicas x 64 (from dw sums)
#define WS_ESUM    2199040                 // [512] 8 replicas x 64
#define WS_SCALREP 2199552                 // [128] 8 reps x 16: 0=sq 1=xn 2=c*emb^2
#define WS_FLAGCNT 2199680                 // [16] int: 1=K2 ticket 2=K3 ticket
#define WS_IDX     2199696                 // [NTOK] int (atomicExch-written)
#define WS_SORT    2232464                 // [NTOK] int (counting sort)
#define WS_OFF     2265232                 // [1024] int

// ---- output layout (float offsets) ----
#define O_Q    0
#define O_CB   2097152
#define O_CM   2097153
#define O_DV   2097154
#define O_PP   2097155
#define O_IDX  2097156
#define O_CS   2129924
#define O_EW   2130948
#define O_EMB  2196484

// 3-word bf16 decomposition: v = h + m + l, each round-to-nearest-even.
__device__ __forceinline__ void hilo3(float v, unsigned &h, unsigned &m, unsigned &l)
{
    unsigned b  = __float_as_uint(v);
    unsigned hb = (b + 0x7FFFu + ((b >> 16) & 1u)) & 0xFFFF0000u;
    float r1    = v - __uint_as_float(hb);
    unsigned b1 = __float_as_uint(r1);
    unsigned mb = (b1 + 0x7FFFu + ((b1 >> 16) & 1u)) & 0xFFFF0000u;
    float r2    = r1 - __uint_as_float(mb);
    unsigned b2 = __float_as_uint(r2);
    l = (b2 + 0x7FFFu + ((b2 >> 16) & 1u)) >> 16;
    h = hb >> 16;
    m = mb >> 16;
}

// ---------------------------------------------------------------------------
// 1) rotate via cross-lane FWHT. Blocks >= 512: zero all accumulators
//    (consumed by later kernels only) + enorm + E h/m/l bf16 prep.
__global__ __launch_bounds__(256) void k_rotate_enorm(const float* __restrict__ x,
    const float* __restrict__ E, float* __restrict__ xr, float* __restrict__ enorm,
    unsigned short* __restrict__ eh, unsigned short* __restrict__ em,
    unsigned short* __restrict__ el,
    float* __restrict__ counts, int* __restrict__ flagc,
    float* __restrict__ e_sum, float* __restrict__ xr_sum,
    float* __restrict__ scalrep)
{
    int tid = threadIdx.x;
    if (blockIdx.x >= 512) {
        int b = (int)blockIdx.x - 512;
        counts[(b << 8) + tid] = 0.f;
        if (b == 0) {
            if (tid < 16) flagc[tid] = 0;
            if (tid < 128) scalrep[tid] = 0.f;
        } else if (b == 1) {
            e_sum[tid] = 0.f; e_sum[256 + tid] = 0.f;
        } else if (b == 2) {
            xr_sum[tid] = 0.f; xr_sum[256 + tid] = 0.f;
        }
        int k = (b << 8) + tid;
        const float* ep = E + ((size_t)k << 6);
        unsigned* ehw = (unsigned*)eh + (k << 5);
        unsigned* emw = (unsigned*)em + (k << 5);
        unsigned* elw = (unsigned*)el + (k << 5);
        float s = 0.f;
        #pragma unroll
        for (int q = 0; q < 32; ++q) {
            float v0 = ep[2*q], v1 = ep[2*q+1];
            s = fmaf(v0, v0, s); s = fmaf(v1, v1, s);
            unsigned h0, m0, l0, h1, m1, l1;
            hilo3(v0, h0, m0, l0);
            hilo3(v1, h1, m1, l1);
            ehw[q] = h0 | (h1 << 16);
            emw[q] = m0 | (m1 << 16);
            elw[q] = l0 | (l1 << 16);
        }
        enorm[k] = s;
        return;
    }
    __shared__ float xt[64 * 65];
    int p  = blockIdx.x >> 4;
    int s0 = ((int)blockIdx.x & 15) << 6;

    {
        const float4* x4 = (const float4*)x;
        #pragma unroll
        for (int pass = 0; pass < 4; ++pass) {
            int q = (pass << 8) + tid;
            int c = q >> 4, col = (q & 15) << 2;
            float4 v = x4[(p << 14) + (c << 8) + (s0 >> 2) + (col >> 2)];
            float* dst = xt + c * 65 + col;
            dst[0] = v.x; dst[1] = v.y; dst[2] = v.z; dst[3] = v.w;
        }
    }
    __syncthreads();

    int lane = tid & 63, w = tid >> 6;
    #pragma unroll
    for (int i = 0; i < 4; ++i) {
        int sl = (w << 4) + (i << 2);
        const float* src = xt + lane * 65 + sl;
        float4 v = make_float4(src[0], src[1], src[2], src[3]);
        #pragma unroll
        for (int s = 1; s <= 32; s <<= 1) {
            float sgn = (lane & s) ? -1.f : 1.f;
            float ox = __shfl_xor(v.x, s);
            float oy = __shfl_xor(v.y, s);
            float oz = __shfl_xor(v.z, s);
            float ow = __shfl_xor(v.w, s);
            v.x = fmaf(sgn, v.x, ox);
            v.y = fmaf(sgn, v.y, oy);
            v.z = fmaf(sgn, v.z, oz);
            v.w = fmaf(sgn, v.w, ow);
        }
        int t0 = ((int)blockIdx.x << 6) + sl;
        float* dst = xr + ((size_t)t0 << 6) + lane;
        dst[0]   = v.x;
        dst[64]  = v.y;
        dst[128] = v.z;
        dst[192] = v.w;
    }
}

// ---------------------------------------------------------------------------
// 2) MFMA argmin, 3-word precision (error ~1e-5 < old f32-fixup path) -> NO
//    fixup needed. r9-proven structure; 12 MFMAs/step. Last-block ticket:
//    scan counts -> off, cs/out_cs/csw, serial counting-sort scatter.
__global__ __launch_bounds__(256, 3) void k_argmin(const float* __restrict__ xr,
    const unsigned short* __restrict__ eh, const unsigned short* __restrict__ em,
    const unsigned short* __restrict__ el, const float* __restrict__ enorm,
    const float* __restrict__ ecs, int* __restrict__ idxw,
    float* __restrict__ out_idx, float* __restrict__ counts,
    float* __restrict__ out_cs, float* __restrict__ csw,
    int* __restrict__ off, int* __restrict__ sorted, int* __restrict__ done_ctr)
{
    __shared__ uint4 ehs[1024];
    __shared__ uint4 ems[1024];
    __shared__ uint4 els[1024];
    __shared__ float ens[128];
    __shared__ float m_b1[32];
    __shared__ int   m_id[32];
    int tid = threadIdx.x;
    int lane = tid & 63, w = tid >> 6;
    int ts = w >> 1, kh = w & 1;
    int tx = lane & 15, gq = lane >> 4;
    int n0 = (int)blockIdx.x << 5;
    int tokbase = n0 + (ts << 4);

    short8 ah0, am0, al0, ah1, am1, al1;
    {
        const float* xp = xr + ((size_t)(tokbase + tx) << 6) + (gq << 3);
        float4 xa = *(const float4*)(xp);
        float4 xb = *(const float4*)(xp + 4);
        float4 xc = *(const float4*)(xp + 32);
        float4 xd = *(const float4*)(xp + 36);
        float a0v[8] = {xa.x,xa.y,xa.z,xa.w,xb.x,xb.y,xb.z,xb.w};
        float a1v[8] = {xc.x,xc.y,xc.z,xc.w,xd.x,xd.y,xd.z,xd.w};
        #pragma unroll
        for (int j = 0; j < 8; ++j) {
            unsigned h, m, l;
            hilo3(a0v[j], h, m, l);
            ah0[j] = (short)h; am0[j] = (short)m; al0[j] = (short)l;
            hilo3(a1v[j], h, m, l);
            ah1[j] = (short)h; am1[j] = (short)m; al1[j] = (short)l;
        }
    }

    float b1[4]; int idx[4];
    #pragma unroll
    for (int r = 0; r < 4; ++r) { b1[r] = 3.4e38f; idx[r] = 0; }

    int swz0 = gq ^ (tx & 7);
    int swz1 = (4 + gq) ^ (tx & 7);
    const f32x4 z4 = {0.f, 0.f, 0.f, 0.f};

    for (int ch = 0; ch < 8; ++ch) {
        int c0 = ch << 7;
        __syncthreads();
        {
            const uint4* ghs = (const uint4*)eh + ((size_t)c0 << 3);
            const uint4* gms = (const uint4*)em + ((size_t)c0 << 3);
            const uint4* gls = (const uint4*)el + ((size_t)c0 << 3);
            #pragma unroll
            for (int i = 0; i < 4; ++i) {
                int u = (i << 8) + tid;
                int rr = u >> 3, bb = u & 7;
                int bs = bb ^ (rr & 7);
                ehs[(rr << 3) + bs] = ghs[u];
                ems[(rr << 3) + bs] = gms[u];
                els[(rr << 3) + bs] = gls[u];
            }
            if (tid < 128) ens[tid] = enorm[c0 + tid];
        }
        __syncthreads();

        #pragma unroll
        for (int s = 0; s < 4; ++s) {
            int rbase = (kh << 6) + (s << 4) + tx;
            short8 bh0 = ((const short8*)ehs)[(rbase << 3) + swz0];
            short8 bh1 = ((const short8*)ehs)[(rbase << 3) + swz1];
            short8 bm0 = ((const short8*)ems)[(rbase << 3) + swz0];
            short8 bm1 = ((const short8*)ems)[(rbase << 3) + swz1];
            short8 bl0 = ((const short8*)els)[(rbase << 3) + swz0];
            short8 bl1 = ((const short8*)els)[(rbase << 3) + swz1];

            // small terms first: al*bh, ah*bl, am*bm, am*bh, ah*bm, ah*bh
            f32x4 a0 = MFMA(al0, bh0, z4, 0, 0, 0);
            a0 = MFMA(ah0, bl0, a0, 0, 0, 0);
            a0 = MFMA(am0, bm0, a0, 0, 0, 0);
            a0 = MFMA(am0, bh0, a0, 0, 0, 0);
            a0 = MFMA(ah0, bm0, a0, 0, 0, 0);
            a0 = MFMA(ah0, bh0, a0, 0, 0, 0);
            f32x4 a1 = MFMA(al1, bh1, z4, 0, 0, 0);
            a1 = MFMA(ah1, bl1, a1, 0, 0, 0);
            a1 = MFMA(am1, bm1, a1, 0, 0, 0);
            a1 = MFMA(am1, bh1, a1, 0, 0, 0);
            a1 = MFMA(ah1, bm1, a1, 0, 0, 0);
            a1 = MFMA(ah1, bh1, a1, 0, 0, 0);

            float en = ens[rbase];
            int kk = c0 + rbase;
            #pragma unroll
            for (int r = 0; r < 4; ++r) {
                float sv = fmaf(-2.f, a0[r], fmaf(-2.f, a1[r], en));
                bool t = sv < b1[r];
                idx[r] = t ? kk : idx[r];
                b1[r] = fminf(b1[r], sv);
            }
        }
    }

    float v1f[4]; int idf[4];
    #pragma unroll
    for (int r = 0; r < 4; ++r) {
        float v1 = b1[r]; int id = idx[r];
        #pragma unroll
        for (int m = 1; m <= 8; m <<= 1) {
            float o1 = __shfl_xor(v1, m);
            int   oi = __shfl_xor(id, m);
            if (o1 < v1 || (o1 == v1 && oi < id)) { v1 = o1; id = oi; }
        }
        v1f[r] = v1; idf[r] = id;
    }

    int tl = (ts << 4) + (gq << 2);
    if (kh == 1 && tx == 0) {
        #pragma unroll
        for (int r = 0; r < 4; ++r) {
            m_b1[tl + r] = v1f[r];
            m_id[tl + r] = idf[r];
        }
    }
    __syncthreads();
    if (kh == 0 && tx == 0) {
        #pragma unroll
        for (int r = 0; r < 4; ++r) {
            float o1 = m_b1[tl + r];
            int   oi = m_id[tl + r];
            float v1 = v1f[r]; int id = idf[r];
            bool t = (o1 < v1) || (o1 == v1 && oi < id);
            int idm = t ? oi : id;
            int tok = tokbase + (gq << 2) + r;
            atomicExch(&idxw[tok], idm);   // RMW: same-kernel ticket reads it
            out_idx[tok] = (float)idm;
            atomicAdd(&counts[idm], 1.f);
        }
    }

    // ---- ticket: last of 1024 blocks: scan -> off/cs -> serial scatter ----
    __shared__ int ticket;
    __syncthreads();                       // drains this block's atomics
    if (tid == 0) ticket = atomicAdd(done_ctr, 1);
    __syncthreads();
    if (ticket != 1023) return;

    int* soff = (int*)ehs;                 // alias staging LDS (done with it)
    int* scur = soff + 1024;
    __shared__ int   wcnt2[4], woff2[4];
    __shared__ float wsum2[4];
    __shared__ float nss;

    int ci4[4]; int s = 0;
    float cs4[4]; float csum = 0.f;
    #pragma unroll
    for (int j = 0; j < 4; ++j) {
        int kk = (tid << 2) + j;
        float c = ALOAD(&counts[kk]);
        ci4[j] = (int)c;
        s += ci4[j];
        float cs = ecs[kk] * 0.99f + 0.01f * c;
        cs4[j] = cs;
        csum += cs;
    }
    int sc = s;
    #pragma unroll
    for (int o = 1; o < 64; o <<= 1) {
        int u = __shfl_up(sc, o);
        if (lane >= o) sc += u;
    }
    float v = csum;
    #pragma unroll
    for (int m = 32; m >= 1; m >>= 1) v += __shfl_xor(v, m);
    if (lane == 63) wcnt2[w] = sc;
    if (lane == 0)  wsum2[w] = v;
    __syncthreads();
    if (tid == 0) {
        int run = 0;
        #pragma unroll
        for (int i = 0; i < 4; ++i) { woff2[i] = run; run += wcnt2[i]; }
        nss = wsum2[0] + wsum2[1] + wsum2[2] + wsum2[3];
    }
    __syncthreads();
    float nn = nss;
    int run = woff2[w] + (sc - s);
    #pragma unroll
    for (int j = 0; j < 4; ++j) {
        int kk = (tid << 2) + j;
        off[kk] = run;
        soff[kk] = run;
        scur[kk] = run;
        run += ci4[j];
        float csf = (cs4[j] + 1e-5f) / (nn + 1024.f * 1e-5f) * nn;
        out_cs[kk] = csf;
        csw[kk] = csf;
    }
    __syncthreads();
    // serial compact scatter (coalesced idxw reads, LDS cursors)
    for (int t = tid; t < NTOK; t += 256) {
        int k = ALOAD(&idxw[t]);
        int pos = atomicAdd(&scur[k], 1);
        sorted[pos] = t;
    }
}

// ---------------------------------------------------------------------------
// 3) fused quant (per-token) + dwemb (per-code, r15-proven staged gather) +
//    last-block finalize. All inputs cross-kernel or same-kernel atomics.
//    (validated verbatim in r19)
__global__ __launch_bounds__(256) void k_quant_dwemb(const float* __restrict__ x,
    const float* __restrict__ xr, const float* __restrict__ E,
    const int* __restrict__ idxw, const int* __restrict__ sorted,
    const int* __restrict__ off, const float* __restrict__ counts,
    const float* __restrict__ csw, const float* __restrict__ emaw,
    float* __restrict__ outq, float* __restrict__ out_ew,
    float* __restrict__ out_emb, float* __restrict__ e_sum,
    float* __restrict__ xr_sum, float* __restrict__ scalrep,
    float* __restrict__ out, int* __restrict__ done_ctr)
{
    __shared__ int   lidx[32];
    __shared__ float wr[4], wn[4];
    __shared__ float part[3][64];
    __shared__ int   seg[2048];
    int tid = threadIdx.x;
    int lane = tid & 63, w = tid >> 6;
    int k = blockIdx.x;

    // ---- part A: quant of tokens [32k, 32k+32) ----
    int n0 = k << 5;
    if (tid < 32) lidx[tid] = idxw[n0 + tid];
    __syncthreads();
    int f40 = k << 9;
    float sq = 0.f, xn = 0.f;
    #pragma unroll
    for (int it = 0; it < 2; ++it) {
        int q = (it << 8) + tid;
        int kk = lidx[q >> 4];
        int d4 = q & 15;
        float4 xv = ((const float4*)x)[f40 + q];
        float4 ev = ((const float4*)E)[(kk << 4) + d4];
        float dx = ev.x - xv.x, dy = ev.y - xv.y, dz = ev.z - xv.z, dw_ = ev.w - xv.w;
        ((float4*)outq)[f40 + q] = make_float4(xv.x + dx, xv.y + dy, xv.z + dz, xv.w + dw_);
        sq += dx*dx + dy*dy + dz*dz + dw_*dw_;
        xn += xv.x*xv.x + xv.y*xv.y + xv.z*xv.z + xv.w*xv.w;
    }
    #pragma unroll
    for (int m = 32; m >= 1; m >>= 1) { sq += __shfl_xor(sq, m); xn += __shfl_xor(xn, m); }
    if (lane == 0) { wr[w] = sq; wn[w] = xn; }
    __syncthreads();
    if (tid == 0) {
        int rep = (k & 7) << 4;
        atomicAdd(&scalrep[rep + 0], wr[0] + wr[1] + wr[2] + wr[3]);
        atomicAdd(&scalrep[rep + 1], wn[0] + wn[1] + wn[2] + wn[3]);
    }

    // ---- part B: dwemb for code k (LDS-staged segment gather) ----
    int d = lane;
    int a = off[k];
    int cnt = (int)counts[k];
    int end = a + cnt;
    float sum = 0.f;
    for (int base = a; base < end; base += 2048) {
        int clen = min(2048, end - base);
        __syncthreads();
        for (int t = tid; t < clen; t += 256) seg[t] = sorted[base + t];
        __syncthreads();
        #pragma unroll 2
        for (int j = w; j < clen; j += 4) {
            int tok = seg[j];
            sum += xr[((size_t)tok << 6) + d];
        }
    }
    __syncthreads();
    if (w) part[w - 1][d] = sum;
    __syncthreads();
    if (w == 0) {
        float dw = sum + part[0][d] + part[1][d] + part[2][d];
        int i = (k << 6) + d;
        float nw = emaw[i] * 0.99f + 0.01f * dw;
        out_ew[i] = nw;
        float emb = nw / csw[k];
        out_emb[i] = emb;
        if (cnt > 0) {
            int rep = (k & 7) << 6;
            atomicAdd(&xr_sum[rep + d], dw);          // Σ_k dw = Σ_tokens xr
            float c = (float)cnt;
            atomicAdd(&e_sum[rep + d], c * emb);
            float t2 = c * emb * emb;
            #pragma unroll
            for (int m = 32; m >= 1; m >>= 1) t2 += __shfl_xor(t2, m);
            if (d == 0) atomicAdd(&scalrep[((k & 7) << 4) + 2], t2);
        }
    }

    // ---- part C: ticket finalize ----
    __shared__ int ticket;
    __syncthreads();                       // drains this block's atomics
    if (tid == 0) ticket = atomicAdd(done_ctr, 1);
    __syncthreads();
    if (ticket != 1023) return;

    __shared__ float wt[4], wd[4];
    float tt = 0.f;
    #pragma unroll
    for (int j = 0; j < 4; ++j) {
        float aa = ALOAD(&counts[(tid << 2) + j]) * (1.f / 32768.f);
        tt += aa * logf(aa + 1e-10f);
    }
    float dc = 0.f;
    if (tid < 64) {
        float xs8 = 0.f, es8 = 0.f;
        #pragma unroll
        for (int r2 = 0; r2 < 8; ++r2) {
            xs8 += ALOAD(&xr_sum[(r2 << 6) + tid]);
            es8 += ALOAD(&e_sum[(r2 << 6) + tid]);
        }
        dc = es8 * xs8;
    }
    #pragma unroll
    for (int m = 32; m >= 1; m >>= 1) { tt += __shfl_xor(tt, m); dc += __shfl_xor(dc, m); }
    if (lane == 0) { wt[w] = tt; wd[w] = dc; }
    __syncthreads();
    if (tid == 0) {
        float S = wt[0] + wt[1] + wt[2] + wt[3];
        float Dt = wd[0] + wd[1] + wd[2] + wd[3];
        float sqs = 0.f, xns = 0.f, s2s = 0.f;
        #pragma unroll
        for (int r2 = 0; r2 < 8; ++r2) {
            sqs += ALOAD(&scalrep[(r2 << 4) + 0]);
            xns += ALOAD(&scalrep[(r2 << 4) + 1]);
            s2s += ALOAD(&scalrep[(r2 << 4) + 2]);
        }
        float cb = sqs * (1.f / 2097152.f);
        out[O_CB] = cb;
        out[O_CM] = 0.25f * cb;
        float inv = 1.f / 32768.f;
        out[O_DV] = s2s * inv + 64.f * xns * inv - 2.f * (Dt * inv * inv);
        out[O_PP] = expf(-S);
    }
}

// ---------------------------------------------------------------------------
extern "C" void kernel_launch(void* const* d_in, const int* in_sizes, int n_in,
                              void* d_out, int out_size, void* d_ws, size_t ws_size,
                              hipStream_t stream)
{
    const float* x    = (const float*)d_in[0];
    const float* E    = (const float*)d_in[1];
    const float* emaw = (const float*)d_in[3];
    const float* ecs  = (const float*)d_in[4];
    float* out = (float*)d_out;
    float* ws  = (float*)d_ws;
    int* flagc = (int*)(ws + WS_FLAGCNT);

    hipLaunchKernelGGL(k_rotate_enorm, dim3(516), dim3(256), 0, stream,
                       x, E, ws + WS_XR, ws + WS_ENORM,
                       (unsigned short*)(ws + WS_EH), (unsigned short*)(ws + WS_EM),
                       (unsigned short*)(ws + WS_EL),
                       ws + WS_COUNTS, flagc,
                       ws + WS_ESUM, ws + WS_XRSUM, ws + WS_SCALREP);
    hipLaunchKernelGGL(k_argmin, dim3(1024), dim3(256), 0, stream,
                       ws + WS_XR, (const unsigned short*)(ws + WS_EH),
                       (const unsigned short*)(ws + WS_EM),
                       (const unsigned short*)(ws + WS_EL), ws + WS_ENORM,
                       ecs, (int*)(ws + WS_IDX), out + O_IDX, ws + WS_COUNTS,
                       out + O_CS, ws + WS_CS, (int*)(ws + WS_OFF),
                       (int*)(ws + WS_SORT), flagc + 1);
    hipLaunchKernelGGL(k_quant_dwemb, dim3(1024), dim3(256), 0, stream,
                       x, ws + WS_XR, E, (const int*)(ws + WS_IDX),
                       (const int*)(ws + WS_SORT), (const int*)(ws + WS_OFF),
                       ws + WS_COUNTS, ws + WS_CS, emaw,
                       out + O_Q, out + O_EW, out + O_EMB,
                       ws + WS_ESUM, ws + WS_XRSUM, ws + WS_SCALREP,
                       out, flagc + 2);
}

// Round 21
// 99.428 us; speedup vs baseline: 1.3039x; 1.3039x over previous
//
#include <hip/hip_runtime.h>
#include <math.h>

#define NTOK 32768
#define KCB  1024
#define DIM  64
#define THETA 0.02f   // hi/lo-bf16 MFMA dist error bound ~1e-3; 20x margin
#define MAXCORR 8192

typedef __attribute__((ext_vector_type(8))) short short8;
typedef __attribute__((ext_vector_type(4))) float f32x4;
#define MFMA __builtin_amdgcn_mfma_f32_16x16x32_bf16
#define ALOAD(p) __hip_atomic_load((p), __ATOMIC_RELAXED, __HIP_MEMORY_SCOPE_AGENT)

// ---- workspace layout (float word offsets) ----
#define WS_XR      0                       // [NTOK*64] rotated vectors f32
#define WS_ENORM   2097152                 // [1024] ||e_k||^2
#define WS_EH      2098176                 // [32768 words] E hi bf16
#define WS_EL      2130944                 // [32768 words] E lo bf16
#define WS_COUNTS  2163712                 // [1024]
#define WS_CS      2164736                 // [1024]
#define WS_XRSUM   2165760                 // [512] 8 replicas x 64 (from dw sums)
#define WS_ESUM    2166272                 // [512] 8 replicas x 64
#define WS_SCALREP 2166784                 // [128] 8 reps x 16: 0=sq 1=xn 2=c*emb^2
#define WS_FLAGCNT 2166912                 // [16] int: 0=corrctr 1=K2tkt 2=K3tkt 3=K4tkt
#define WS_IDX     2166928                 // [NTOK] int
#define WS_FLAG    2199696                 // [NTOK] int per-token near-tie flag
#define WS_SORT    2232464                 // [NTOK] int (pre-fixup counting sort)
#define WS_OFF     2265232                 // [1024] int (pre-fixup offsets)
#define WS_CUR     2266256                 // [1024] int
#define WS_PCNT    2267280                 // [1024] int (pre-fixup counts)
#define WS_CORR    2268304                 // [2*MAXCORR] int (tok, old<<10|new)

// ---- output layout (float offsets) ----
#define O_Q    0
#define O_CB   2097152
#define O_CM   2097153
#define O_DV   2097154
#define O_PP   2097155
#define O_IDX  2097156
#define O_CS   2129924
#define O_EW   2130948
#define O_EMB  2196484

__device__ __forceinline__ void hilo(float v, unsigned &h, unsigned &l)
{
    unsigned b  = __float_as_uint(v);
    unsigned hb = (b + 0x7FFFu + ((b >> 16) & 1u)) & 0xFFFF0000u;
    float lof   = v - __uint_as_float(hb);
    unsigned lb = __float_as_uint(lof);
    l = (lb + 0x7FFFu + ((lb >> 16) & 1u)) >> 16;
    h = hb >> 16;
}

// ---------------------------------------------------------------------------
// 1) rotate via cross-lane FWHT. Blocks >= 512: zero all accumulators
//    (consumed by later kernels only) + enorm + E hi/lo prep. (r14/r17-proven)
__global__ __launch_bounds__(256) void k_rotate_enorm(const float* __restrict__ x,
    const float* __restrict__ E, float* __restrict__ xr, float* __restrict__ enorm,
    unsigned short* __restrict__ eh, unsigned short* __restrict__ el,
    float* __restrict__ counts, int* __restrict__ flagc,
    float* __restrict__ e_sum, float* __restrict__ xr_sum,
    float* __restrict__ scalrep)
{
    int tid = threadIdx.x;
    if (blockIdx.x >= 512) {
        int b = (int)blockIdx.x - 512;
        counts[(b << 8) + tid] = 0.f;
        if (b == 0) {
            if (tid < 16) flagc[tid] = 0;
            if (tid < 128) scalrep[tid] = 0.f;
        } else if (b == 1) {
            e_sum[tid] = 0.f; e_sum[256 + tid] = 0.f;
        } else if (b == 2) {
            xr_sum[tid] = 0.f; xr_sum[256 + tid] = 0.f;
        }
        int k = (b << 8) + tid;
        const float* ep = E + ((size_t)k << 6);
        unsigned* ehw = (unsigned*)eh + (k << 5);
        unsigned* elw = (unsigned*)el + (k << 5);
        float s = 0.f;
        #pragma unroll
        for (int q = 0; q < 32; ++q) {
            float v0 = ep[2*q], v1 = ep[2*q+1];
            s = fmaf(v0, v0, s); s = fmaf(v1, v1, s);
            unsigned h0, l0, h1, l1;
            hilo(v0, h0, l0);
            hilo(v1, h1, l1);
            ehw[q] = h0 | (h1 << 16);
            elw[q] = l0 | (l1 << 16);
        }
        enorm[k] = s;
        return;
    }
    __shared__ float xt[64 * 65];
    int p  = blockIdx.x >> 4;
    int s0 = ((int)blockIdx.x & 15) << 6;

    {
        const float4* x4 = (const float4*)x;
        #pragma unroll
        for (int pass = 0; pass < 4; ++pass) {
            int q = (pass << 8) + tid;
            int c = q >> 4, col = (q & 15) << 2;
            float4 v = x4[(p << 14) + (c << 8) + (s0 >> 2) + (col >> 2)];
            float* dst = xt + c * 65 + col;
            dst[0] = v.x; dst[1] = v.y; dst[2] = v.z; dst[3] = v.w;
        }
    }
    __syncthreads();

    int lane = tid & 63, w = tid >> 6;
    #pragma unroll
    for (int i = 0; i < 4; ++i) {
        int sl = (w << 4) + (i << 2);
        const float* src = xt + lane * 65 + sl;
        float4 v = make_float4(src[0], src[1], src[2], src[3]);
        #pragma unroll
        for (int s = 1; s <= 32; s <<= 1) {
            float sgn = (lane & s) ? -1.f : 1.f;
            float ox = __shfl_xor(v.x, s);
            float oy = __shfl_xor(v.y, s);
            float oz = __shfl_xor(v.z, s);
            float ow = __shfl_xor(v.w, s);
            v.x = fmaf(sgn, v.x, ox);
            v.y = fmaf(sgn, v.y, oy);
            v.z = fmaf(sgn, v.z, oz);
            v.w = fmaf(sgn, v.w, ow);
        }
        int t0 = ((int)blockIdx.x << 6) + sl;
        float* dst = xr + ((size_t)t0 << 6) + lane;
        dst[0]   = v.x;
        dst[64]  = v.y;
        dst[128] = v.z;
        dst[192] = v.w;
    }
}

// ---------------------------------------------------------------------------
// 2) MFMA argmin, LDS-staged (r9/r14-proven) + flag[] output. Last-block
//    ticket runs the exclusive scan of PRE-fixup counts -> off/cur/pcnt.
__global__ __launch_bounds__(256, 4) void k_argmin(const float* __restrict__ xr,
    const unsigned short* __restrict__ eh, const unsigned short* __restrict__ el,
    const float* __restrict__ enorm, int* __restrict__ idxw,
    float* __restrict__ out_idx, float* __restrict__ counts,
    int* __restrict__ flag, int* __restrict__ off, int* __restrict__ cur,
    int* __restrict__ pcnt, int* __restrict__ done_ctr)
{
    __shared__ uint4 ehs[1024];
    __shared__ uint4 els[1024];
    __shared__ float ens[128];
    __shared__ float m_b1[32], m_b2[32];
    __shared__ int   m_id[32];
    int tid = threadIdx.x;
    int lane = tid & 63, w = tid >> 6;
    int ts = w >> 1, kh = w & 1;
    int tx = lane & 15, gq = lane >> 4;
    int tokbase = ((int)blockIdx.x << 5) + (ts << 4);

    short8 ah0, al0, ah1, al1;
    {
        const float* xp = xr + ((size_t)(tokbase + tx) << 6) + (gq << 3);
        float4 xa = *(const float4*)(xp);
        float4 xb = *(const float4*)(xp + 4);
        float4 xc = *(const float4*)(xp + 32);
        float4 xd = *(const float4*)(xp + 36);
        float a0v[8] = {xa.x,xa.y,xa.z,xa.w,xb.x,xb.y,xb.z,xb.w};
        float a1v[8] = {xc.x,xc.y,xc.z,xc.w,xd.x,xd.y,xd.z,xd.w};
        #pragma unroll
        for (int j = 0; j < 8; ++j) {
            unsigned h, l;
            hilo(a0v[j], h, l);
            ah0[j] = (short)h; al0[j] = (short)l;
            hilo(a1v[j], h, l);
            ah1[j] = (short)h; al1[j] = (short)l;
        }
    }

    float b1[4], b2[4]; int idx[4];
    #pragma unroll
    for (int r = 0; r < 4; ++r) { b1[r] = 3.4e38f; b2[r] = 3.4e38f; idx[r] = 0; }

    int swz0 = gq ^ (tx & 7);
    int swz1 = (4 + gq) ^ (tx & 7);
    const f32x4 z4 = {0.f, 0.f, 0.f, 0.f};

    for (int ch = 0; ch < 8; ++ch) {
        int c0 = ch << 7;
        __syncthreads();
        {
            const uint4* ghs = (const uint4*)eh + ((size_t)c0 << 3);
            const uint4* gls = (const uint4*)el + ((size_t)c0 << 3);
            #pragma unroll
            for (int i = 0; i < 4; ++i) {
                int u = (i << 8) + tid;
                int rr = u >> 3, bb = u & 7;
                int bs = bb ^ (rr & 7);
                ehs[(rr << 3) + bs] = ghs[u];
                els[(rr << 3) + bs] = gls[u];
            }
            if (tid < 128) ens[tid] = enorm[c0 + tid];
        }
        __syncthreads();

        #pragma unroll
        for (int s = 0; s < 4; ++s) {
            int rbase = (kh << 6) + (s << 4) + tx;
            short8 bh0 = ((const short8*)ehs)[(rbase << 3) + swz0];
            short8 bh1 = ((const short8*)ehs)[(rbase << 3) + swz1];
            short8 bl0 = ((const short8*)els)[(rbase << 3) + swz0];
            short8 bl1 = ((const short8*)els)[(rbase << 3) + swz1];

            f32x4 a0 = MFMA(ah0, bh0, z4, 0, 0, 0);
            a0 = MFMA(ah0, bl0, a0, 0, 0, 0);
            a0 = MFMA(al0, bh0, a0, 0, 0, 0);
            f32x4 a1 = MFMA(ah1, bh1, z4, 0, 0, 0);
            a1 = MFMA(ah1, bl1, a1, 0, 0, 0);
            a1 = MFMA(al1, bh1, a1, 0, 0, 0);

            float en = ens[rbase];
            int kk = c0 + rbase;
            #pragma unroll
            for (int r = 0; r < 4; ++r) {
                float sv = fmaf(-2.f, a0[r], fmaf(-2.f, a1[r], en));
                float mx = fmaxf(sv, b1[r]);
                b2[r] = fminf(b2[r], mx);
                bool t = sv < b1[r];
                idx[r] = t ? kk : idx[r];
                b1[r] = fminf(b1[r], sv);
            }
        }
    }

    float v1f[4], v2f[4]; int idf[4];
    #pragma unroll
    for (int r = 0; r < 4; ++r) {
        float v1 = b1[r], v2 = b2[r]; int id = idx[r];
        #pragma unroll
        for (int m = 1; m <= 8; m <<= 1) {
            float o1 = __shfl_xor(v1, m);
            float o2 = __shfl_xor(v2, m);
            int   oi = __shfl_xor(id, m);
            float nb2 = fminf(fminf(v2, o2), fmaxf(v1, o1));
            bool t = (o1 < v1) || (o1 == v1 && oi < id);
            v1 = t ? o1 : v1;
            id = t ? oi : id;
            v2 = nb2;
        }
        v1f[r] = v1; v2f[r] = v2; idf[r] = id;
    }

    int tl = (ts << 4) + (gq << 2);
    if (kh == 1 && tx == 0) {
        #pragma unroll
        for (int r = 0; r < 4; ++r) {
            m_b1[tl + r] = v1f[r];
            m_b2[tl + r] = v2f[r];
            m_id[tl + r] = idf[r];
        }
    }
    __syncthreads();
    if (kh == 0 && tx == 0) {
        #pragma unroll
        for (int r = 0; r < 4; ++r) {
            float o1 = m_b1[tl + r], o2 = m_b2[tl + r];
            int   oi = m_id[tl + r];
            float v1 = v1f[r]; int id = idf[r];
            float b2m = fminf(fminf(v2f[r], o2), fmaxf(v1, o1));
            bool t = (o1 < v1) || (o1 == v1 && oi < id);
            float v1m = t ? o1 : v1;
            int   idm = t ? oi : id;
            int tok = tokbase + (gq << 2) + r;
            idxw[tok] = idm;
            out_idx[tok] = (float)idm;
            atomicAdd(&counts[idm], 1.f);
            flag[tok] = (b2m - v1m < THETA) ? 1 : 0;
        }
    }

    // ---- ticket: last of 1024 blocks scans PRE-fixup counts -> off/cur/pcnt
    __shared__ int ticket;
    __syncthreads();                       // drains this block's atomics
    if (tid == 0) ticket = atomicAdd(done_ctr, 1);
    __syncthreads();
    if (ticket != 1023) return;

    __shared__ int wcnt2[4], woff2[4];
    int ci4[4]; int s = 0;
    #pragma unroll
    for (int j = 0; j < 4; ++j) {
        int kk = (tid << 2) + j;
        ci4[j] = (int)ALOAD(&counts[kk]);
        s += ci4[j];
    }
    int sc = s;
    #pragma unroll
    for (int o = 1; o < 64; o <<= 1) {
        int u = __shfl_up(sc, o);
        if (lane >= o) sc += u;
    }
    if (lane == 63) wcnt2[w] = sc;
    __syncthreads();
    if (tid == 0) {
        int run = 0;
        #pragma unroll
        for (int i = 0; i < 4; ++i) { woff2[i] = run; run += wcnt2[i]; }
    }
    __syncthreads();
    int run = woff2[w] + (sc - s);
    #pragma unroll
    for (int j = 0; j < 4; ++j) {
        int kk = (tid << 2) + j;
        off[kk] = run;
        cur[kk] = run;
        pcnt[kk] = ci4[j];
        run += ci4[j];
    }
}

// ---------------------------------------------------------------------------
// 3) scatter (pre-fixup idx) + block-local fixup (-> correction list) +
//    quant (corrected) + sq/xn; last-block ticket computes cs (post counts).
__global__ __launch_bounds__(256) void k_fixupquant_cs(const float* __restrict__ x,
    const float* __restrict__ xr, const float* __restrict__ E,
    const float* __restrict__ enorm, const float* __restrict__ ecs,
    const int* __restrict__ flag, int* __restrict__ idxw,
    float* __restrict__ out_idx, float* __restrict__ counts,
    float* __restrict__ out_cs, float* __restrict__ csw,
    int* __restrict__ cur, int* __restrict__ sorted,
    int* __restrict__ corrctr, int* __restrict__ corr,
    int* __restrict__ done_ctr, float* __restrict__ outq,
    float* __restrict__ scalrep)
{
    __shared__ int lidx[32];
    __shared__ unsigned fmask;
    __shared__ float wr[4], wn[4];
    int tid = threadIdx.x;
    int lane = tid & 63, w = tid >> 6;
    int n0 = (int)blockIdx.x << 5;

    int fl = 0;
    if (tid < 32) {
        int k = idxw[n0 + tid];
        lidx[tid] = k;
        fl = flag[n0 + tid];
        int pos = atomicAdd(&cur[k], 1);   // scatter with PRE-fixup idx
        sorted[pos] = n0 + tid;
    }
    unsigned long long bal = __ballot(fl != 0);
    if (tid == 0) fmask = (unsigned)bal;
    __syncthreads();

    // wave-parallel exact rescan of this block's flagged tokens
    unsigned msk = fmask;
    int widx = 0;
    while (msk) {
        int src = __ffs(msk) - 1; msk &= msk - 1;
        if ((widx++ & 3) != w) continue;
        int tok = n0 + src;
        const float4* xp = (const float4*)(xr + ((size_t)tok << 6));
        float4 xa[16];
        #pragma unroll
        for (int q = 0; q < 16; ++q) xa[q] = xp[q];
        float best = 3.4e38f; int bidx = 0;
        for (int c = 0; c < 16; ++c) {
            int k = (c << 6) + lane;
            const float4* epp = (const float4*)(E + ((size_t)k << 6));
            float d = 0.f;
            #pragma unroll
            for (int q = 0; q < 16; ++q) {
                float4 e = epp[q];
                d = fmaf(xa[q].x, e.x, d);
                d = fmaf(xa[q].y, e.y, d);
                d = fmaf(xa[q].z, e.z, d);
                d = fmaf(xa[q].w, e.w, d);
            }
            float sv = fmaf(-2.f, d, enorm[k]);
            if (sv < best) { best = sv; bidx = k; }
        }
        #pragma unroll
        for (int m = 1; m <= 32; m <<= 1) {
            float ov = __shfl_xor(best, m);
            int   oi = __shfl_xor(bidx, m);
            if (ov < best || (ov == best && oi < bidx)) { best = ov; bidx = oi; }
        }
        if (lane == 0) {
            int old = lidx[src];
            if (old != bidx) {
                atomicAdd(&counts[old], -1.f);
                atomicAdd(&counts[bidx], 1.f);
                lidx[src] = bidx;
                idxw[tok] = bidx;
                out_idx[tok] = (float)bidx;
                int p = atomicAdd(corrctr, 1);
                if (p < MAXCORR) {
                    corr[2*p]   = tok;
                    corr[2*p+1] = (old << 10) | bidx;
                }
            }
        }
    }
    __syncthreads();

    // quant + sq + xn (corrected lidx); Σ||xr||² = 64·Σ||x||² (Hadamard)
    int f40 = (int)blockIdx.x << 9;
    float sq = 0.f, xn = 0.f;
    #pragma unroll
    for (int it = 0; it < 2; ++it) {
        int q = (it << 8) + tid;
        int kk = lidx[q >> 4];
        int d4 = q & 15;
        float4 xv = ((const float4*)x)[f40 + q];
        float4 ev = ((const float4*)E)[(kk << 4) + d4];
        float dx = ev.x - xv.x, dy = ev.y - xv.y, dz = ev.z - xv.z, dw_ = ev.w - xv.w;
        ((float4*)outq)[f40 + q] = make_float4(xv.x + dx, xv.y + dy, xv.z + dz, xv.w + dw_);
        sq += dx*dx + dy*dy + dz*dz + dw_*dw_;
        xn += xv.x*xv.x + xv.y*xv.y + xv.z*xv.z + xv.w*xv.w;
    }
    #pragma unroll
    for (int m = 32; m >= 1; m >>= 1) { sq += __shfl_xor(sq, m); xn += __shfl_xor(xn, m); }
    if (lane == 0) { wr[w] = sq; wn[w] = xn; }
    __syncthreads();
    if (tid == 0) {
        int rep = ((int)blockIdx.x & 7) << 4;
        atomicAdd(&scalrep[rep + 0], wr[0] + wr[1] + wr[2] + wr[3]);
        atomicAdd(&scalrep[rep + 1], wn[0] + wn[1] + wn[2] + wn[3]);
    }

    // ---- ticket: last of 1024 blocks computes cs from POST-fixup counts ----
    __shared__ int ticket;
    __syncthreads();                       // drains this block's atomics
    if (tid == 0) ticket = atomicAdd(done_ctr, 1);
    __syncthreads();
    if (ticket != 1023) return;

    __shared__ float wsum2[4];
    __shared__ float nss;
    float cs4[4];
    float csum = 0.f;
    #pragma unroll
    for (int j = 0; j < 4; ++j) {
        int kk = (tid << 2) + j;
        float c = ALOAD(&counts[kk]);
        float cs = ecs[kk] * 0.99f + 0.01f * c;
        cs4[j] = cs;
        csum += cs;
    }
    float v = csum;
    #pragma unroll
    for (int m = 32; m >= 1; m >>= 1) v += __shfl_xor(v, m);
    if (lane == 0) wsum2[w] = v;
    __syncthreads();
    if (tid == 0) nss = wsum2[0] + wsum2[1] + wsum2[2] + wsum2[3];
    __syncthreads();
    float nn = nss;
    #pragma unroll
    for (int j = 0; j < 4; ++j) {
        int kk = (tid << 2) + j;
        float csf = (cs4[j] + 1e-5f) / (nn + 1024.f * 1e-5f) * nn;
        out_cs[kk] = csf;
        csw[kk] = csf;
    }
}

// ---------------------------------------------------------------------------
// 4) dwemb over PRE-fixup segments (r15-proven LDS-staged gather) with
//    correction-list adjustment, + last-block finalize.
__global__ __launch_bounds__(256) void k_dwemb_final(const float* __restrict__ xr,
    const int* __restrict__ sorted, const int* __restrict__ off,
    const int* __restrict__ pcnt, const float* __restrict__ counts,
    const float* __restrict__ csw, const float* __restrict__ emaw,
    const int* __restrict__ corrctr, const int* __restrict__ corr,
    float* __restrict__ out_ew, float* __restrict__ out_emb,
    float* __restrict__ e_sum, float* __restrict__ scalrep,
    float* __restrict__ xr_sum, float* __restrict__ out,
    int* __restrict__ done_ctr)
{
    __shared__ float part[3][64];
    __shared__ int   seg[2048];
    int k = blockIdx.x;
    int tid = threadIdx.x;
    int w = tid >> 6, d = tid & 63;
    int a = off[k];
    int cntp = pcnt[k];
    int end = a + cntp;

    float sum = 0.f;
    for (int base = a; base < end; base += 2048) {
        int clen = min(2048, end - base);
        __syncthreads();
        for (int t = tid; t < clen; t += 256) seg[t] = sorted[base + t];
        __syncthreads();
        #pragma unroll 2
        for (int j = w; j < clen; j += 4) {
            int tok = seg[j];
            sum += xr[((size_t)tok << 6) + d];
        }
    }
    __syncthreads();
    if (w) part[w - 1][d] = sum;
    __syncthreads();
    if (w == 0) {
        float dw = sum + part[0][d] + part[1][d] + part[2][d];
        // apply rare fixup corrections (tok moved old->new)
        int nc = min(corrctr[0], MAXCORR);
        for (int i = 0; i < nc; ++i) {
            int tok = corr[2*i];
            int on  = corr[2*i+1];
            int ok = on >> 10, nk = on & 1023;
            if (ok == k) dw -= xr[((size_t)tok << 6) + d];
            if (nk == k) dw += xr[((size_t)tok << 6) + d];
        }
        int cnt = (int)counts[k];          // POST-fixup count
        int i = (k << 6) + d;
        float nw = emaw[i] * 0.99f + 0.01f * dw;
        out_ew[i] = nw;
        float emb = nw / csw[k];
        out_emb[i] = emb;
        if (cnt > 0) {
            int rep = (k & 7) << 6;
            atomicAdd(&xr_sum[rep + d], dw);          // Σ_k dw = Σ_tokens xr
            float c = (float)cnt;
            atomicAdd(&e_sum[rep + d], c * emb);
            float t2 = c * emb * emb;
            #pragma unroll
            for (int m = 32; m >= 1; m >>= 1) t2 += __shfl_xor(t2, m);
            if (d == 0) atomicAdd(&scalrep[((k & 7) << 4) + 2], t2);
        }
    }

    // ---- ticket: last of 1024 blocks finalizes the scalar losses ----
    __shared__ int ticket;
    __syncthreads();                       // drains each wave's atomics
    if (tid == 0) ticket = atomicAdd(done_ctr, 1);
    __syncthreads();
    if (ticket != 1023) return;

    __shared__ float wt[4], wd[4];
    float tt = 0.f;
    #pragma unroll
    for (int j = 0; j < 4; ++j) {
        float aa = ALOAD(&counts[(tid << 2) + j]) * (1.f / 32768.f);
        tt += aa * logf(aa + 1e-10f);
    }
    float dc = 0.f;
    if (tid < 64) {
        float xs8 = 0.f, es8 = 0.f;
        #pragma unroll
        for (int r2 = 0; r2 < 8; ++r2) {
            xs8 += ALOAD(&xr_sum[(r2 << 6) + tid]);
            es8 += ALOAD(&e_sum[(r2 << 6) + tid]);
        }
        dc = es8 * xs8;
    }
    #pragma unroll
    for (int m = 32; m >= 1; m >>= 1) { tt += __shfl_xor(tt, m); dc += __shfl_xor(dc, m); }
    if ((tid & 63) == 0) { wt[w] = tt; wd[w] = dc; }
    __syncthreads();
    if (tid == 0) {
        float S = wt[0] + wt[1] + wt[2] + wt[3];
        float Dt = wd[0] + wd[1] + wd[2] + wd[3];
        float sqs = 0.f, xns = 0.f, s2s = 0.f;
        #pragma unroll
        for (int r2 = 0; r2 < 8; ++r2) {
            sqs += scalrep[(r2 << 4) + 0];             // prior kernel
            xns += scalrep[(r2 << 4) + 1];             // prior kernel
            s2s += ALOAD(&scalrep[(r2 << 4) + 2]);     // this kernel
        }
        float cb = sqs * (1.f / 2097152.f);
        out[O_CB] = cb;
        out[O_CM] = 0.25f * cb;
        float inv = 1.f / 32768.f;
        out[O_DV] = s2s * inv + 64.f * xns * inv - 2.f * (Dt * inv * inv);
        out[O_PP] = expf(-S);
    }
}

// ---------------------------------------------------------------------------
extern "C" void kernel_launch(void* const* d_in, const int* in_sizes, int n_in,
                              void* d_out, int out_size, void* d_ws, size_t ws_size,
                              hipStream_t stream)
{
    const float* x    = (const float*)d_in[0];
    const float* E    = (const float*)d_in[1];
    const float* emaw = (const float*)d_in[3];
    const float* ecs  = (const float*)d_in[4];
    float* out = (float*)d_out;
    float* ws  = (float*)d_ws;
    int* flagc = (int*)(ws + WS_FLAGCNT);

    hipLaunchKernelGGL(k_rotate_enorm, dim3(516), dim3(256), 0, stream,
                       x, E, ws + WS_XR, ws + WS_ENORM,
                       (unsigned short*)(ws + WS_EH), (unsigned short*)(ws + WS_EL),
                       ws + WS_COUNTS, flagc,
                       ws + WS_ESUM, ws + WS_XRSUM, ws + WS_SCALREP);
    hipLaunchKernelGGL(k_argmin, dim3(1024), dim3(256), 0, stream,
                       ws + WS_XR, (const unsigned short*)(ws + WS_EH),
                       (const unsigned short*)(ws + WS_EL), ws + WS_ENORM,
                       (int*)(ws + WS_IDX), out + O_IDX, ws + WS_COUNTS,
                       (int*)(ws + WS_FLAG), (int*)(ws + WS_OFF),
                       (int*)(ws + WS_CUR), (int*)(ws + WS_PCNT), flagc + 1);
    hipLaunchKernelGGL(k_fixupquant_cs, dim3(1024), dim3(256), 0, stream,
                       x, ws + WS_XR, E, ws + WS_ENORM, ecs,
                       (const int*)(ws + WS_FLAG), (int*)(ws + WS_IDX),
                       out + O_IDX, ws + WS_COUNTS, out + O_CS, ws + WS_CS,
                       (int*)(ws + WS_CUR), (int*)(ws + WS_SORT),
                       flagc, (int*)(ws + WS_CORR), flagc + 2,
                       out + O_Q, ws + WS_SCALREP);
    hipLaunchKernelGGL(k_dwemb_final, dim3(1024), dim3(256), 0, stream,
                       ws + WS_XR, (const int*)(ws + WS_SORT),
                       (const int*)(ws + WS_OFF), (const int*)(ws + WS_PCNT),
                       ws + WS_COUNTS, ws + WS_CS, emaw,
                       (const int*)flagc, (const int*)(ws + WS_CORR),
                       out + O_EW, out + O_EMB, ws + WS_ESUM,
                       ws + WS_SCALREP, ws + WS_XRSUM, out, flagc + 3);
}